// Round 1
// baseline (18726.250 us; speedup 1.0000x reference)
//
#include <hip/hip_runtime.h>
#include <cstdint>
#include <cstddef>

// ---------------------------------------------------------------------------
// 2-layer LSTM (B=256, S=1024, V=H=256) + FC + log_softmax, MI355X/gfx950.
//
// Phases (all on `stream`):
//   0. pack_w        : f32 weights -> bf16 MFMA B-fragment layout (once).
//   1. pre_gemm      : pre = in @ W_ih^T + b_ih + b_hh  (bf16, chunk of 256 t)
//   2. lstm_rec      : persistent recurrence, 256 WGs = 16 Mgroups x 16 Nslices;
//                      per-step cross-WG h exchange via agent-scope atomics.
//   3. fc_lsm        : logits = h2 @ fc_w^T + fc_b, row log_softmax -> d_out.
//
// Workspace (~406 MB): packed weights (2.1MB) | cnt (256KB) | c_state (256KB)
//                      | pre chunk (134MB) | h1 (134MB) | h2 (134MB)
// ---------------------------------------------------------------------------

typedef __attribute__((ext_vector_type(8))) short bf16x8;
typedef __attribute__((ext_vector_type(4))) float f32x4;

#define DEVFN __device__ __forceinline__

constexpr int S_LEN  = 1024;
constexpr int TCHUNK = 256;

DEVFN unsigned short f2bf(float f) {
  union { float f; unsigned u; } v; v.f = f;
  unsigned r = v.u + 0x7FFFu + ((v.u >> 16) & 1u);   // RNE
  return (unsigned short)(r >> 16);
}
DEVFN float bf2f(unsigned short b) {
  union { unsigned u; float f; } v; v.u = ((unsigned)b) << 16;
  return v.f;
}
// XOR swizzle inside a [rows][512B] LDS tile: 16B slot ^= (row&7)
DEVFN int swz(int row, int colbyte) {
  return row * 512 + ((((colbyte >> 4) ^ (row & 7)) << 4) | (colbyte & 15));
}
DEVFN float sigm(float x) { return 1.f / (1.f + __expf(-x)); }

// --------------------------------------------------------------------------
// Pack W[col][k] (K=256) into B-fragment tiles:
//   dst[((nt*8+kt)*64+lane)*8 + j] = bf16( W[nt*16+(lane&15)][kt*32+(lane>>4)*8+j] )
// grid = (ncols/16)*8 blocks of 64 threads.
// --------------------------------------------------------------------------
__global__ void pack_w(const float* __restrict__ w, unsigned short* __restrict__ dst) {
  int bid = blockIdx.x;           // nt*8 + kt
  int lane = threadIdx.x;
  int col = (bid >> 3) * 16 + (lane & 15);
  int k0  = (bid & 7) * 32 + (lane >> 4) * 8;
  const float* src = w + (size_t)col * 256 + k0;
  unsigned short* d = dst + ((size_t)bid * 64 + lane) * 8;
#pragma unroll
  for (int j = 0; j < 8; ++j) d[j] = f2bf(src[j]);
}

// --------------------------------------------------------------------------
// pre = A @ W^T + (b_ih + b_hh), one TCHUNK of timesteps.
// A is x (f32, [B][S][V]) when AF32, else h1 (bf16, [S][B][H]).
// Output pre: [TCHUNK][256 b][1024 col] bf16.
// Block = 512 thr (8 waves), tile = [64 rows][1024 cols], rows = (tloc, 64 b's).
// grid = 1024 (tloc = bid>>2, b0 = (bid&3)*64).
// --------------------------------------------------------------------------
template<bool AF32>
__global__ __launch_bounds__(512, 2) void pre_gemm(
    const void* __restrict__ Asrc, const unsigned short* __restrict__ Bp,
    const float* __restrict__ bih, const float* __restrict__ bhh,
    unsigned short* __restrict__ pre, int t0)
{
  __shared__ char Alds[32768];        // [64 rows][512B] bf16, swizzled
  const int tid = threadIdx.x;
  const int wid = tid >> 6, lane = tid & 63;
  const int tloc = blockIdx.x >> 2, b0 = (blockIdx.x & 3) * 64;

  { // stage A tile -> LDS (bf16)
    int r  = tid >> 3;                 // 0..63 (row within tile = b offset)
    int c0 = (tid & 7) * 32;           // k start, 32 elems per thread
    if (AF32) {
      const float* s = (const float*)Asrc +
          (((size_t)(b0 + r)) * S_LEN + (size_t)(t0 + tloc)) * 256 + c0;
      const float4* s4p = (const float4*)s;
      float4 vv[8];
#pragma unroll
      for (int j = 0; j < 8; ++j) vv[j] = s4p[j];
#pragma unroll
      for (int s4 = 0; s4 < 4; ++s4) {
        uint4 o;
        o.x = f2bf(vv[2*s4].x)   | ((unsigned)f2bf(vv[2*s4].y)   << 16);
        o.y = f2bf(vv[2*s4].z)   | ((unsigned)f2bf(vv[2*s4].w)   << 16);
        o.z = f2bf(vv[2*s4+1].x) | ((unsigned)f2bf(vv[2*s4+1].y) << 16);
        o.w = f2bf(vv[2*s4+1].z) | ((unsigned)f2bf(vv[2*s4+1].w) << 16);
        *(uint4*)(&Alds[swz(r, c0 * 2 + s4 * 16)]) = o;
      }
    } else {
      const unsigned short* s = (const unsigned short*)Asrc +
          (((size_t)(t0 + tloc) * 256 + (b0 + r)) * 256 + c0);
      const uint4* s4p = (const uint4*)s;
#pragma unroll
      for (int s4 = 0; s4 < 4; ++s4)
        *(uint4*)(&Alds[swz(r, c0 * 2 + s4 * 16)]) = s4p[s4];
    }
  }
  __syncthreads();

  f32x4 acc[4][8];
#pragma unroll
  for (int mt = 0; mt < 4; ++mt)
#pragma unroll
    for (int j = 0; j < 8; ++j) acc[mt][j] = (f32x4){0.f, 0.f, 0.f, 0.f};

#pragma unroll
  for (int kt = 0; kt < 8; ++kt) {
    bf16x8 a[4];
#pragma unroll
    for (int mt = 0; mt < 4; ++mt)
      a[mt] = *(const bf16x8*)(&Alds[swz(mt * 16 + (lane & 15),
                                         kt * 64 + (lane >> 4) * 16)]);
#pragma unroll
    for (int j = 0; j < 8; ++j) {
      bf16x8 b = *(const bf16x8*)(Bp +
          (((size_t)(wid * 8 + j) * 8 + kt) * 64 + lane) * 8);
#pragma unroll
      for (int mt = 0; mt < 4; ++mt)
        acc[mt][j] = __builtin_amdgcn_mfma_f32_16x16x32_bf16(a[mt], b, acc[mt][j], 0, 0, 0);
    }
  }

#pragma unroll
  for (int j = 0; j < 8; ++j) {
    int col = (wid * 8 + j) * 16 + (lane & 15);
    float bias = bih[col] + bhh[col];
#pragma unroll
    for (int mt = 0; mt < 4; ++mt) {
#pragma unroll
      for (int q = 0; q < 4; ++q) {
        int rl = mt * 16 + (lane >> 4) * 4 + q;    // C row = 4*(lane>>4)+q
        pre[((size_t)tloc * 256 + b0 + rl) * 1024 + col] = f2bf(acc[mt][j][q] + bias);
      }
    }
  }
}

// --------------------------------------------------------------------------
// Persistent LSTM recurrence over one TCHUNK.
// grid = 256 WGs of 256 thr: bid = n*16 + m  (m = batch group, n = unit slice;
// n-major so the 16 peers of an m-group share an XCD under bid%8 placement).
// Wave g (=tid>>6) computes gate g for units [16n,16n+16) over its 16 batch rows.
// W_hh slice lives in VGPRs (bw[8]); c lives in f32 registers of gate threads.
// Per-step h exchange: bf16-pair atomic stores -> release counter -> acquire
// spin -> relaxed atomic dword loads (agent scope: correct across XCDs).
// hout layout: [S][256 b][256 k] bf16 (doubles as h1/h2 storage).
// --------------------------------------------------------------------------
__global__ __launch_bounds__(256, 1) void lstm_rec(
    const unsigned short* __restrict__ pre,
    const unsigned short* __restrict__ Whh,
    unsigned short* __restrict__ hout,
    float* __restrict__ cst,
    unsigned int* __restrict__ cnt,
    int t0)
{
  __shared__ char  hlds[8192];          // h[16 rows][512B] bf16, swizzled
  __shared__ float aclds[4][16][16];    // gate preacts [g][row][unit]
  const int tid = threadIdx.x;
  const int g = tid >> 6, lane = tid & 63;
  const int m = blockIdx.x & 15, n = blockIdx.x >> 4;

  // W_hh B-fragments, resident in registers: n-tile = g*16+n
  bf16x8 bw[8];
#pragma unroll
  for (int kt = 0; kt < 8; ++kt)
    bw[kt] = *(const bf16x8*)(Whh + (((size_t)(g * 16 + n) * 8 + kt) * 64 + lane) * 8);

  const bool gth = tid < 128;           // gate-math threads: (row ir, unit pair p)
  const int ir = tid >> 3, p = tid & 7;
  float c0 = 0.f, c1 = 0.f;
  if (gth) {
    c0 = cst[(size_t)(16 * m + ir) * 256 + 16 * n + 2 * p];
    c1 = cst[(size_t)(16 * m + ir) * 256 + 16 * n + 2 * p + 1];
  }
  const int hr = tid >> 4, dg = tid & 15;  // h-read mapping: row hr, 32B group dg

  for (int tl = 0; tl < TCHUNK; ++tl) {
    const int t = t0 + tl;

    // prefetch this step's input pre-activations (independent of h)
    unsigned pd0 = 0, pd1 = 0, pd2 = 0, pd3 = 0;
    if (gth) {
      const unsigned* pb = (const unsigned*)(pre +
          ((size_t)tl * 256 + 16 * m + ir) * 1024);
      pd0 = pb[0 * 128 + 8 * n + p];
      pd1 = pb[1 * 128 + 8 * n + p];
      pd2 = pb[2 * 128 + 8 * n + p];
      pd3 = pb[3 * 128 + 8 * n + p];
    }

    f32x4 acc = (f32x4){0.f, 0.f, 0.f, 0.f};
    if (t > 0) {
      if (tl > 0) {                      // wait for all 16 peers' h[t-1]
        if (tid == 0) {
          unsigned int* cp = cnt + ((size_t)(tl - 1) * 16 + m) * 16;
          while (__hip_atomic_load(cp, __ATOMIC_ACQUIRE, __HIP_MEMORY_SCOPE_AGENT) < 16u)
            __builtin_amdgcn_s_sleep(1);
        }
        __syncthreads();
      } // tl==0: h[t0-1] was written by the previous chunk's kernel.

      unsigned* hs = (unsigned*)hout +
          (((size_t)(t - 1) * 256 + 16 * m + hr) * 128 + dg * 8);
      unsigned hv[8];
#pragma unroll
      for (int j = 0; j < 8; ++j)
        hv[j] = __hip_atomic_load(hs + j, __ATOMIC_RELAXED, __HIP_MEMORY_SCOPE_AGENT);
      *(uint4*)(&hlds[swz(hr, dg * 32)])      = make_uint4(hv[0], hv[1], hv[2], hv[3]);
      *(uint4*)(&hlds[swz(hr, dg * 32 + 16)]) = make_uint4(hv[4], hv[5], hv[6], hv[7]);
      __syncthreads();

#pragma unroll
      for (int kt = 0; kt < 8; ++kt) {
        bf16x8 a = *(const bf16x8*)(&hlds[swz(lane & 15,
                                              kt * 64 + (lane >> 4) * 16)]);
        acc = __builtin_amdgcn_mfma_f32_16x16x32_bf16(a, bw[kt], acc, 0, 0, 0);
      }
    }

    // dump gate preacts (C layout: row=4*(lane>>4)+q, col=lane&15)
#pragma unroll
    for (int q = 0; q < 4; ++q)
      aclds[g][(lane >> 4) * 4 + q][lane & 15] = acc[q];
    __syncthreads();

    if (gth) {
      float h0, h1v;
      {
        float ia = aclds[0][ir][2 * p]     + bf2f((unsigned short)(pd0 & 0xFFFFu));
        float fa = aclds[1][ir][2 * p]     + bf2f((unsigned short)(pd1 & 0xFFFFu));
        float ga = aclds[2][ir][2 * p]     + bf2f((unsigned short)(pd2 & 0xFFFFu));
        float oa = aclds[3][ir][2 * p]     + bf2f((unsigned short)(pd3 & 0xFFFFu));
        c0 = sigm(fa) * c0 + sigm(ia) * tanhf(ga);
        h0 = sigm(oa) * tanhf(c0);
      }
      {
        float ia = aclds[0][ir][2 * p + 1] + bf2f((unsigned short)(pd0 >> 16));
        float fa = aclds[1][ir][2 * p + 1] + bf2f((unsigned short)(pd1 >> 16));
        float ga = aclds[2][ir][2 * p + 1] + bf2f((unsigned short)(pd2 >> 16));
        float oa = aclds[3][ir][2 * p + 1] + bf2f((unsigned short)(pd3 >> 16));
        c1 = sigm(fa) * c1 + sigm(ia) * tanhf(ga);
        h1v = sigm(oa) * tanhf(c1);
      }
      unsigned hw = (unsigned)f2bf(h0) | ((unsigned)f2bf(h1v) << 16);
      unsigned* hp = (unsigned*)hout +
          (((size_t)t * 256 + 16 * m + ir) * 128 + 8 * n + p);
      __hip_atomic_store(hp, hw, __ATOMIC_RELAXED, __HIP_MEMORY_SCOPE_AGENT);
    }
    __syncthreads();   // drains vmcnt: all publish stores globally visible
    if (tid == 0)
      __hip_atomic_fetch_add(cnt + ((size_t)tl * 16 + m) * 16, 1u,
                             __ATOMIC_RELEASE, __HIP_MEMORY_SCOPE_AGENT);
  }

  if (gth) {
    cst[(size_t)(16 * m + ir) * 256 + 16 * n + 2 * p]     = c0;
    cst[(size_t)(16 * m + ir) * 256 + 16 * n + 2 * p + 1] = c1;
  }
}

// --------------------------------------------------------------------------
// logits = h2 @ fc_w^T + fc_b; out = logits - logsumexp(logits) (rows of 256).
// Block = 256 thr (4 waves); tile = 64 rows (fixed t, 64 b's) x 256 cols.
// grid = 4096 (t = bid>>2, b0 = (bid&3)*64).
// --------------------------------------------------------------------------
__global__ __launch_bounds__(256, 1) void fc_lsm(
    const unsigned short* __restrict__ h2,
    const unsigned short* __restrict__ Bp,
    const float* __restrict__ fcb,
    float* __restrict__ out)
{
  const int tid = threadIdx.x;
  const int wid = tid >> 6, lane = tid & 63;
  const int t = blockIdx.x >> 2, b0 = (blockIdx.x & 3) * 64;

  f32x4 acc[16];
#pragma unroll
  for (int nt = 0; nt < 16; ++nt) acc[nt] = (f32x4){0.f, 0.f, 0.f, 0.f};

#pragma unroll
  for (int kt = 0; kt < 8; ++kt) {
    bf16x8 a = *(const bf16x8*)(h2 +
        (((size_t)t * 256 + b0 + wid * 16 + (lane & 15)) * 256 +
         kt * 32 + (lane >> 4) * 8));
#pragma unroll
    for (int nt = 0; nt < 16; ++nt) {
      bf16x8 b = *(const bf16x8*)(Bp + (((size_t)nt * 8 + kt) * 64 + lane) * 8);
      acc[nt] = __builtin_amdgcn_mfma_f32_16x16x32_bf16(a, b, acc[nt], 0, 0, 0);
    }
  }
#pragma unroll
  for (int nt = 0; nt < 16; ++nt) {
    float bias = fcb[nt * 16 + (lane & 15)];
#pragma unroll
    for (int q = 0; q < 4; ++q) acc[nt][q] += bias;
  }

  float mx[4] = {-1e30f, -1e30f, -1e30f, -1e30f};
#pragma unroll
  for (int nt = 0; nt < 16; ++nt)
#pragma unroll
    for (int q = 0; q < 4; ++q) mx[q] = fmaxf(mx[q], acc[nt][q]);
#pragma unroll
  for (int d = 1; d < 16; d <<= 1)
#pragma unroll
    for (int q = 0; q < 4; ++q) mx[q] = fmaxf(mx[q], __shfl_xor(mx[q], d, 64));

  float sm[4] = {0.f, 0.f, 0.f, 0.f};
#pragma unroll
  for (int nt = 0; nt < 16; ++nt)
#pragma unroll
    for (int q = 0; q < 4; ++q) sm[q] += __expf(acc[nt][q] - mx[q]);
#pragma unroll
  for (int d = 1; d < 16; d <<= 1)
#pragma unroll
    for (int q = 0; q < 4; ++q) sm[q] += __shfl_xor(sm[q], d, 64);

  float lse[4];
#pragma unroll
  for (int q = 0; q < 4; ++q) lse[q] = mx[q] + __logf(sm[q]);

#pragma unroll
  for (int nt = 0; nt < 16; ++nt) {
#pragma unroll
    for (int q = 0; q < 4; ++q) {
      int b = b0 + wid * 16 + (lane >> 4) * 4 + q;
      out[((size_t)b * 1024 + t) * 256 + nt * 16 + (lane & 15)] = acc[nt][q] - lse[q];
    }
  }
}

// Unambiguous marker if workspace is too small.
__global__ void fill_marker(float* out, size_t nvals) {
  size_t i = (size_t)blockIdx.x * blockDim.x + threadIdx.x;
  if (i < nvals) out[i] = -7777.0f;
}

// --------------------------------------------------------------------------
extern "C" void kernel_launch(void* const* d_in, const int* in_sizes, int n_in,
                              void* d_out, int out_size, void* d_ws, size_t ws_size,
                              hipStream_t stream)
{
  (void)in_sizes; (void)n_in;
  const float* x    = (const float*)d_in[0];
  const float* wih0 = (const float*)d_in[1];
  const float* whh0 = (const float*)d_in[2];
  const float* bih0 = (const float*)d_in[3];
  const float* bhh0 = (const float*)d_in[4];
  const float* wih1 = (const float*)d_in[5];
  const float* whh1 = (const float*)d_in[6];
  const float* bih1 = (const float*)d_in[7];
  const float* bhh1 = (const float*)d_in[8];
  const float* fcw  = (const float*)d_in[9];
  const float* fcb  = (const float*)d_in[10];
  float* out = (float*)d_out;

  // workspace layout (bytes)
  const size_t o_wp0i = 0;
  const size_t o_wp0h = o_wp0i + 524288;
  const size_t o_wp1i = o_wp0h + 524288;
  const size_t o_wp1h = o_wp1i + 524288;
  const size_t o_fcp  = o_wp1h + 524288;        // 131072
  const size_t o_cnt  = o_fcp  + 131072;        // 262144
  const size_t o_cst  = o_cnt  + 262144;        // 262144
  const size_t o_pre  = o_cst  + 262144;        // 134217728
  const size_t o_h1   = o_pre  + 134217728;     // 134217728
  const size_t o_h2   = o_h1   + 134217728;     // 134217728
  const size_t need   = o_h2   + 134217728;     // ~406 MB

  if (ws_size < need) {
    size_t nv = (size_t)out_size;
    fill_marker<<<(unsigned)((nv + 1023) / 1024), 1024, 0, stream>>>(out, nv);
    return;
  }

  char* ws = (char*)d_ws;
  unsigned short* wp0i = (unsigned short*)(ws + o_wp0i);
  unsigned short* wp0h = (unsigned short*)(ws + o_wp0h);
  unsigned short* wp1i = (unsigned short*)(ws + o_wp1i);
  unsigned short* wp1h = (unsigned short*)(ws + o_wp1h);
  unsigned short* fcp  = (unsigned short*)(ws + o_fcp);
  unsigned int*   cnt  = (unsigned int*)(ws + o_cnt);
  float*          cst  = (float*)(ws + o_cst);
  unsigned short* pre  = (unsigned short*)(ws + o_pre);
  unsigned short* h1   = (unsigned short*)(ws + o_h1);
  unsigned short* h2   = (unsigned short*)(ws + o_h2);

  pack_w<<<512, 64, 0, stream>>>(wih0, wp0i);
  pack_w<<<512, 64, 0, stream>>>(whh0, wp0h);
  pack_w<<<512, 64, 0, stream>>>(wih1, wp1i);
  pack_w<<<512, 64, 0, stream>>>(whh1, wp1h);
  pack_w<<<128, 64, 0, stream>>>(fcw,  fcp);

  // ----- layer 0 -----
  hipMemsetAsync(cst, 0, 262144, stream);
  for (int c = 0; c < 4; ++c) {
    int t0 = c * TCHUNK;
    pre_gemm<true><<<1024, 512, 0, stream>>>(x, wp0i, bih0, bhh0, pre, t0);
    hipMemsetAsync(cnt, 0, 262144, stream);
    lstm_rec<<<256, 256, 0, stream>>>(pre, wp0h, h1, cst, cnt, t0);
  }
  // ----- layer 1 -----
  hipMemsetAsync(cst, 0, 262144, stream);
  for (int c = 0; c < 4; ++c) {
    int t0 = c * TCHUNK;
    pre_gemm<false><<<1024, 512, 0, stream>>>(h1, wp1i, bih1, bhh1, pre, t0);
    hipMemsetAsync(cnt, 0, 262144, stream);
    lstm_rec<<<256, 256, 0, stream>>>(pre, wp1h, h2, cst, cnt, t0);
  }
  // ----- FC + log_softmax -----
  fc_lsm<<<4096, 256, 0, stream>>>(h2, fcp, fcb, out);
}

// Round 2
// 7938.142 us; speedup vs baseline: 2.3590x; 2.3590x over previous
//
#include <hip/hip_runtime.h>
#include <cstdint>
#include <cstddef>

// ---------------------------------------------------------------------------
// 2-layer LSTM (B=256, S=1024, V=H=256) + FC + log_softmax, MI355X/gfx950.
//
// Round 2: sentinel-spin h-exchange (no counters, no fences), lane-local gate
// math (128 WGs x 128 thr, W_hh slice in VGPRs), pre in [t][b][u][gate] layout.
//
// Phases (all on `stream`):
//   0. pack_w        : f32 weights -> bf16 MFMA B-fragment layout (once).
//   1. pre_gemm      : pre = in @ W_ih^T + b_ih + b_hh  (bf16, chunk of 256 t)
//   2. lstm_rec      : recurrence, 128 WGs = 16 Mgroups x 8 unit-slices;
//                      per-step h exchange by spinning on sentinel-initialized
//                      hout dwords (relaxed agent atomics, one L3 RT).
//   3. fc_lsm        : logits = h2 @ fc_w^T + fc_b, row log_softmax -> d_out.
// ---------------------------------------------------------------------------

typedef __attribute__((ext_vector_type(8))) short bf16x8;
typedef __attribute__((ext_vector_type(4))) float f32x4;

#define DEVFN __device__ __forceinline__

constexpr int S_LEN  = 1024;
constexpr int TCHUNK = 256;
constexpr unsigned SENT = 0xFFFFFFFFu;   // bf16 NaN pair: unreachable for tanh outputs

DEVFN unsigned short f2bf(float f) {
  union { float f; unsigned u; } v; v.f = f;
  unsigned r = v.u + 0x7FFFu + ((v.u >> 16) & 1u);   // RNE
  return (unsigned short)(r >> 16);
}
DEVFN float bf2f(unsigned short b) {
  union { unsigned u; float f; } v; v.u = ((unsigned)b) << 16;
  return v.f;
}
// XOR swizzle inside a [rows][512B] LDS tile: 16B slot ^= (row&7)
DEVFN int swz(int row, int colbyte) {
  return row * 512 + ((((colbyte >> 4) ^ (row & 7)) << 4) | (colbyte & 15));
}
DEVFN float sigm(float x) { return __builtin_amdgcn_rcpf(1.f + __expf(-x)); }
DEVFN float tanhfast(float x) {
  float ax = fabsf(x);
  float e  = __expf(-2.f * ax);
  float t  = (1.f - e) * __builtin_amdgcn_rcpf(1.f + e);
  return copysignf(t, x);
}

// --------------------------------------------------------------------------
// Pack W[col][k] (K=256) into B-fragment tiles:
//   dst[((nt*8+kt)*64+lane)*8 + j] = bf16( W[nt*16+(lane&15)][kt*32+(lane>>4)*8+j] )
// grid = (ncols/16)*8 blocks of 64 threads.
// --------------------------------------------------------------------------
__global__ void pack_w(const float* __restrict__ w, unsigned short* __restrict__ dst) {
  int bid = blockIdx.x;           // nt*8 + kt
  int lane = threadIdx.x;
  int col = (bid >> 3) * 16 + (lane & 15);
  int k0  = (bid & 7) * 32 + (lane >> 4) * 8;
  const float* src = w + (size_t)col * 256 + k0;
  unsigned short* d = dst + ((size_t)bid * 64 + lane) * 8;
#pragma unroll
  for (int j = 0; j < 8; ++j) d[j] = f2bf(src[j]);
}

// --------------------------------------------------------------------------
// pre = A @ W^T + (b_ih + b_hh), one TCHUNK of timesteps.
// A is x (f32, [B][S][V]) when AF32, else h1 (bf16, [S][B][H]).
// Output pre layout: [TCHUNK][256 b][256 u][4 g] bf16 (gate quad contiguous).
// Block = 512 thr (8 waves), tile = [64 rows][1024 cols], rows = (tloc, 64 b's).
// grid = 1024 (tloc = bid>>2, b0 = (bid&3)*64).
// --------------------------------------------------------------------------
template<bool AF32>
__global__ __launch_bounds__(512, 2) void pre_gemm(
    const void* __restrict__ Asrc, const unsigned short* __restrict__ Bp,
    const float* __restrict__ bih, const float* __restrict__ bhh,
    unsigned short* __restrict__ pre, int t0)
{
  __shared__ char Alds[32768];        // [64 rows][512B] bf16, swizzled
  const int tid = threadIdx.x;
  const int wid = tid >> 6, lane = tid & 63;
  const int tloc = blockIdx.x >> 2, b0 = (blockIdx.x & 3) * 64;

  { // stage A tile -> LDS (bf16)
    int r  = tid >> 3;                 // 0..63 (row within tile = b offset)
    int c0 = (tid & 7) * 32;           // k start, 32 elems per thread
    if (AF32) {
      const float* s = (const float*)Asrc +
          (((size_t)(b0 + r)) * S_LEN + (size_t)(t0 + tloc)) * 256 + c0;
      const float4* s4p = (const float4*)s;
      float4 vv[8];
#pragma unroll
      for (int j = 0; j < 8; ++j) vv[j] = s4p[j];
#pragma unroll
      for (int s4 = 0; s4 < 4; ++s4) {
        uint4 o;
        o.x = f2bf(vv[2*s4].x)   | ((unsigned)f2bf(vv[2*s4].y)   << 16);
        o.y = f2bf(vv[2*s4].z)   | ((unsigned)f2bf(vv[2*s4].w)   << 16);
        o.z = f2bf(vv[2*s4+1].x) | ((unsigned)f2bf(vv[2*s4+1].y) << 16);
        o.w = f2bf(vv[2*s4+1].z) | ((unsigned)f2bf(vv[2*s4+1].w) << 16);
        *(uint4*)(&Alds[swz(r, c0 * 2 + s4 * 16)]) = o;
      }
    } else {
      const unsigned short* s = (const unsigned short*)Asrc +
          (((size_t)(t0 + tloc) * 256 + (b0 + r)) * 256 + c0);
      const uint4* s4p = (const uint4*)s;
#pragma unroll
      for (int s4 = 0; s4 < 4; ++s4)
        *(uint4*)(&Alds[swz(r, c0 * 2 + s4 * 16)]) = s4p[s4];
    }
  }
  __syncthreads();

  f32x4 acc[4][8];
#pragma unroll
  for (int mt = 0; mt < 4; ++mt)
#pragma unroll
    for (int j = 0; j < 8; ++j) acc[mt][j] = (f32x4){0.f, 0.f, 0.f, 0.f};

#pragma unroll
  for (int kt = 0; kt < 8; ++kt) {
    bf16x8 a[4];
#pragma unroll
    for (int mt = 0; mt < 4; ++mt)
      a[mt] = *(const bf16x8*)(&Alds[swz(mt * 16 + (lane & 15),
                                         kt * 64 + (lane >> 4) * 16)]);
#pragma unroll
    for (int j = 0; j < 8; ++j) {
      bf16x8 b = *(const bf16x8*)(Bp +
          (((size_t)(wid * 8 + j) * 8 + kt) * 64 + lane) * 8);
#pragma unroll
      for (int mt = 0; mt < 4; ++mt)
        acc[mt][j] = __builtin_amdgcn_mfma_f32_16x16x32_bf16(a[mt], b, acc[mt][j], 0, 0, 0);
    }
  }

#pragma unroll
  for (int j = 0; j < 8; ++j) {
    int col = (wid * 8 + j) * 16 + (lane & 15);
    float bias = bih[col] + bhh[col];
    int g = col >> 8, u = col & 255;
#pragma unroll
    for (int mt = 0; mt < 4; ++mt) {
#pragma unroll
      for (int q = 0; q < 4; ++q) {
        int rl = mt * 16 + (lane >> 4) * 4 + q;    // C row = 4*(lane>>4)+q
        pre[(((size_t)tloc * 256 + b0 + rl) * 256 + u) * 4 + g] =
            f2bf(acc[mt][j][q] + bias);
      }
    }
  }
}

// --------------------------------------------------------------------------
// LSTM recurrence over one TCHUNK. grid = 128 WGs of 128 thr (2 waves):
// bid = n*16 + m  (m = batch group 0..15, n = unit slice 0..7; n-major so the
// 8 peers of an m-group share an XCD under the bid%8 placement heuristic).
// Wave w owns unit-tile u16 = n*2+w: 16 units x ALL 4 gates (nt = g*16+u16),
// so (i,f,g,o) of a unit are lane-local in acc[0..3]. W_hh fragments (128
// VGPRs) stay register-resident; c state in f32 registers.
// Per-step h exchange: relaxed agent stores into sentinel-initialized hout;
// consumers spin-load the data dwords themselves (one L3 RT, no counters).
// hout layout: [S][256 b][256 u] bf16.
// --------------------------------------------------------------------------
__global__ __launch_bounds__(128, 1) void lstm_rec(
    const unsigned short* __restrict__ pre,
    const unsigned short* __restrict__ Whh,
    unsigned short* __restrict__ hout,
    float* __restrict__ cst,
    int t0)
{
  __shared__ char hlds[8192];           // h[16 rows][512B] bf16, swizzled
  const int tid = threadIdx.x;
  const int w = tid >> 6, lane = tid & 63;
  const int m = blockIdx.x & 15, n = blockIdx.x >> 4;
  const int u16 = n * 2 + w;            // unit-tile 0..15
  const int u   = u16 * 16 + (lane & 15);
  const int r0  = (lane >> 4) * 4;      // first of this lane's 4 C rows

  // W_hh B-fragments, register-resident: nt = g*16 + u16
  bf16x8 bw[4][8];
#pragma unroll
  for (int g = 0; g < 4; ++g)
#pragma unroll
    for (int kt = 0; kt < 8; ++kt)
      bw[g][kt] = *(const bf16x8*)(Whh +
          ((((size_t)(g * 16 + u16)) * 8 + kt) * 64 + lane) * 8);

  float c[4];
#pragma unroll
  for (int q = 0; q < 4; ++q)
    c[q] = cst[(size_t)(16 * m + r0 + q) * 256 + u];

  for (int tl = 0; tl < TCHUNK; ++tl) {
    const int t = t0 + tl;

    // prefetch this step's input pre-activation gate quads (independent of h)
    uint2 pd[4];
#pragma unroll
    for (int q = 0; q < 4; ++q)
      pd[q] = *(const uint2*)(pre +
          (((size_t)tl * 256 + 16 * m + r0 + q) * 256 + u) * 4);

    f32x4 acc[4];
#pragma unroll
    for (int g = 0; g < 4; ++g) acc[g] = (f32x4){0.f, 0.f, 0.f, 0.f};

    if (t > 0) {
      // spin-load h[t-1] tile (16 rows x 128 dwords); thread owns dword col tid
      const unsigned* hs = (const unsigned*)hout + ((size_t)(t - 1) * 256 + 16 * m) * 128;
      unsigned hv[16];
#pragma unroll
      for (int k = 0; k < 16; ++k)
        hv[k] = __hip_atomic_load(hs + k * 128 + tid,
                                  __ATOMIC_RELAXED, __HIP_MEMORY_SCOPE_AGENT);
      unsigned pend = 0;
#pragma unroll
      for (int k = 0; k < 16; ++k) pend |= (hv[k] == SENT) ? (1u << k) : 0u;
      while (pend) {
#pragma unroll
        for (int k = 0; k < 16; ++k)
          if (pend & (1u << k))
            hv[k] = __hip_atomic_load(hs + k * 128 + tid,
                                      __ATOMIC_RELAXED, __HIP_MEMORY_SCOPE_AGENT);
        unsigned np = 0;
#pragma unroll
        for (int k = 0; k < 16; ++k) np |= (hv[k] == SENT) ? (1u << k) : 0u;
        pend = np;
      }
#pragma unroll
      for (int k = 0; k < 16; ++k)
        *(unsigned*)(&hlds[swz(k, tid * 4)]) = hv[k];
      __syncthreads();                   // C: hlds ready

#pragma unroll
      for (int kt = 0; kt < 8; ++kt) {
        bf16x8 a = *(const bf16x8*)(&hlds[swz(lane & 15,
                                              kt * 64 + (lane >> 4) * 16)]);
#pragma unroll
        for (int g = 0; g < 4; ++g)
          acc[g] = __builtin_amdgcn_mfma_f32_16x16x32_bf16(a, bw[g][kt], acc[g], 0, 0, 0);
      }
      __syncthreads();                   // F: reads done before next overwrite
    }

    // lane-local gate math: acc[g][q] is gate g, row r0+q, unit u
    unsigned myh[4];
#pragma unroll
    for (int q = 0; q < 4; ++q) {
      float ia = acc[0][q] + bf2f((unsigned short)(pd[q].x & 0xFFFFu));
      float fa = acc[1][q] + bf2f((unsigned short)(pd[q].x >> 16));
      float ga = acc[2][q] + bf2f((unsigned short)(pd[q].y & 0xFFFFu));
      float oa = acc[3][q] + bf2f((unsigned short)(pd[q].y >> 16));
      c[q] = sigm(fa) * c[q] + sigm(ia) * tanhfast(ga);
      myh[q] = (unsigned)f2bf(sigm(oa) * tanhfast(c[q]));
    }
    // pack (u even, u odd) pairs via lane exchange; even lanes publish dwords
#pragma unroll
    for (int q = 0; q < 4; ++q) {
      unsigned ov = (unsigned)__shfl_xor((int)myh[q], 1, 64);
      if ((lane & 1) == 0) {
        unsigned word = (myh[q] & 0xFFFFu) | (ov << 16);
        unsigned* hp = (unsigned*)hout +
            (((size_t)t * 256 + 16 * m + r0 + q) * 256 + u) / 2;
        __hip_atomic_store(hp, word, __ATOMIC_RELAXED, __HIP_MEMORY_SCOPE_AGENT);
      }
    }
  }

#pragma unroll
  for (int q = 0; q < 4; ++q)
    cst[(size_t)(16 * m + r0 + q) * 256 + u] = c[q];
}

// --------------------------------------------------------------------------
// logits = h2 @ fc_w^T + fc_b; out = logits - logsumexp(logits) (rows of 256).
// Block = 256 thr (4 waves); tile = 64 rows (fixed t, 64 b's) x 256 cols.
// grid = 4096 (t = bid>>2, b0 = (bid&3)*64).
// --------------------------------------------------------------------------
__global__ __launch_bounds__(256, 1) void fc_lsm(
    const unsigned short* __restrict__ h2,
    const unsigned short* __restrict__ Bp,
    const float* __restrict__ fcb,
    float* __restrict__ out)
{
  const int tid = threadIdx.x;
  const int wid = tid >> 6, lane = tid & 63;
  const int t = blockIdx.x >> 2, b0 = (blockIdx.x & 3) * 64;

  f32x4 acc[16];
#pragma unroll
  for (int nt = 0; nt < 16; ++nt) acc[nt] = (f32x4){0.f, 0.f, 0.f, 0.f};

#pragma unroll
  for (int kt = 0; kt < 8; ++kt) {
    bf16x8 a = *(const bf16x8*)(h2 +
        (((size_t)t * 256 + b0 + wid * 16 + (lane & 15)) * 256 +
         kt * 32 + (lane >> 4) * 8));
#pragma unroll
    for (int nt = 0; nt < 16; ++nt) {
      bf16x8 b = *(const bf16x8*)(Bp + (((size_t)nt * 8 + kt) * 64 + lane) * 8);
      acc[nt] = __builtin_amdgcn_mfma_f32_16x16x32_bf16(a, b, acc[nt], 0, 0, 0);
    }
  }
#pragma unroll
  for (int nt = 0; nt < 16; ++nt) {
    float bias = fcb[nt * 16 + (lane & 15)];
#pragma unroll
    for (int q = 0; q < 4; ++q) acc[nt][q] += bias;
  }

  float mx[4] = {-1e30f, -1e30f, -1e30f, -1e30f};
#pragma unroll
  for (int nt = 0; nt < 16; ++nt)
#pragma unroll
    for (int q = 0; q < 4; ++q) mx[q] = fmaxf(mx[q], acc[nt][q]);
#pragma unroll
  for (int d = 1; d < 16; d <<= 1)
#pragma unroll
    for (int q = 0; q < 4; ++q) mx[q] = fmaxf(mx[q], __shfl_xor(mx[q], d, 64));

  float sm[4] = {0.f, 0.f, 0.f, 0.f};
#pragma unroll
  for (int nt = 0; nt < 16; ++nt)
#pragma unroll
    for (int q = 0; q < 4; ++q) sm[q] += __expf(acc[nt][q] - mx[q]);
#pragma unroll
  for (int d = 1; d < 16; d <<= 1)
#pragma unroll
    for (int q = 0; q < 4; ++q) sm[q] += __shfl_xor(sm[q], d, 64);

  float lse[4];
#pragma unroll
  for (int q = 0; q < 4; ++q) lse[q] = mx[q] + __logf(sm[q]);

#pragma unroll
  for (int nt = 0; nt < 16; ++nt) {
#pragma unroll
    for (int q = 0; q < 4; ++q) {
      int b = b0 + wid * 16 + (lane >> 4) * 4 + q;
      out[((size_t)b * 1024 + t) * 256 + nt * 16 + (lane & 15)] = acc[nt][q] - lse[q];
    }
  }
}

// Unambiguous marker if workspace is too small.
__global__ void fill_marker(float* out, size_t nvals) {
  size_t i = (size_t)blockIdx.x * blockDim.x + threadIdx.x;
  if (i < nvals) out[i] = -7777.0f;
}

// --------------------------------------------------------------------------
extern "C" void kernel_launch(void* const* d_in, const int* in_sizes, int n_in,
                              void* d_out, int out_size, void* d_ws, size_t ws_size,
                              hipStream_t stream)
{
  (void)in_sizes; (void)n_in;
  const float* x    = (const float*)d_in[0];
  const float* wih0 = (const float*)d_in[1];
  const float* whh0 = (const float*)d_in[2];
  const float* bih0 = (const float*)d_in[3];
  const float* bhh0 = (const float*)d_in[4];
  const float* wih1 = (const float*)d_in[5];
  const float* whh1 = (const float*)d_in[6];
  const float* bih1 = (const float*)d_in[7];
  const float* bhh1 = (const float*)d_in[8];
  const float* fcw  = (const float*)d_in[9];
  const float* fcb  = (const float*)d_in[10];
  float* out = (float*)d_out;

  // workspace layout (bytes)
  const size_t o_wp0i = 0;
  const size_t o_wp0h = o_wp0i + 524288;
  const size_t o_wp1i = o_wp0h + 524288;
  const size_t o_wp1h = o_wp1i + 524288;
  const size_t o_fcp  = o_wp1h + 524288;        // 131072
  const size_t o_cst  = o_fcp  + 131072;        // 262144
  const size_t o_pre  = o_cst  + 262144;        // 134217728
  const size_t o_h1   = o_pre  + 134217728;     // 134217728
  const size_t o_h2   = o_h1   + 134217728;     // 134217728
  const size_t need   = o_h2   + 134217728;     // ~405 MB

  if (ws_size < need) {
    size_t nv = (size_t)out_size;
    fill_marker<<<(unsigned)((nv + 1023) / 1024), 1024, 0, stream>>>(out, nv);
    return;
  }

  char* ws = (char*)d_ws;
  unsigned short* wp0i = (unsigned short*)(ws + o_wp0i);
  unsigned short* wp0h = (unsigned short*)(ws + o_wp0h);
  unsigned short* wp1i = (unsigned short*)(ws + o_wp1i);
  unsigned short* wp1h = (unsigned short*)(ws + o_wp1h);
  unsigned short* fcp  = (unsigned short*)(ws + o_fcp);
  float*          cst  = (float*)(ws + o_cst);
  unsigned short* pre  = (unsigned short*)(ws + o_pre);
  unsigned short* h1   = (unsigned short*)(ws + o_h1);
  unsigned short* h2   = (unsigned short*)(ws + o_h2);

  pack_w<<<512, 64, 0, stream>>>(wih0, wp0i);
  pack_w<<<512, 64, 0, stream>>>(whh0, wp0h);
  pack_w<<<512, 64, 0, stream>>>(wih1, wp1i);
  pack_w<<<512, 64, 0, stream>>>(whh1, wp1h);
  pack_w<<<128, 64, 0, stream>>>(fcw,  fcp);

  // sentinel-init both h buffers (0xFF bytes -> 0xFFFFFFFF dwords)
  hipMemsetAsync(h1, 0xFF, 134217728, stream);
  hipMemsetAsync(h2, 0xFF, 134217728, stream);

  // ----- layer 0 -----
  hipMemsetAsync(cst, 0, 262144, stream);
  for (int c = 0; c < 4; ++c) {
    int t0 = c * TCHUNK;
    pre_gemm<true><<<1024, 512, 0, stream>>>(x, wp0i, bih0, bhh0, pre, t0);
    lstm_rec<<<128, 128, 0, stream>>>(pre, wp0h, h1, cst, t0);
  }
  // ----- layer 1 -----
  hipMemsetAsync(cst, 0, 262144, stream);
  for (int c = 0; c < 4; ++c) {
    int t0 = c * TCHUNK;
    pre_gemm<false><<<1024, 512, 0, stream>>>(h1, wp1i, bih1, bhh1, pre, t0);
    lstm_rec<<<128, 128, 0, stream>>>(pre, wp1h, h2, cst, t0);
  }
  // ----- FC + log_softmax -----
  fc_lsm<<<4096, 256, 0, stream>>>(h2, fcp, fcb, out);
}

// Round 3
// 3831.431 us; speedup vs baseline: 4.8875x; 2.0718x over previous
//
#include <hip/hip_runtime.h>
#include <cstdint>
#include <cstddef>

// ---------------------------------------------------------------------------
// 2-layer LSTM (B=256, S=1024, V=H=256) + FC + log_softmax, MI355X/gfx950.
//
// Round 3: both layers pipelined in ONE persistent dispatch (256 WGs =
// 128 L0 + 128 L1); ih-contribution computed on the fly (no pre buffer, no
// pre_gemm); flat sentinel-spin rounds; c-state fully register-resident.
//
// Phases: pack_w x5 -> memset h1/h2 sentinels -> lstm_dual -> fc_lsm.
// Workspace ~271 MB: packed weights (2.2MB) | h1 (134MB) | h2 (134MB)
// ---------------------------------------------------------------------------

typedef __attribute__((ext_vector_type(8))) short bf16x8;
typedef __attribute__((ext_vector_type(4))) float f32x4;

#define DEVFN __device__ __forceinline__

constexpr unsigned SENT = 0xFFFFFFFFu;   // bf16 NaN pair: unreachable for tanh outputs

DEVFN unsigned short f2bf(float f) {
  union { float f; unsigned u; } v; v.f = f;
  unsigned r = v.u + 0x7FFFu + ((v.u >> 16) & 1u);   // RNE
  return (unsigned short)(r >> 16);
}
DEVFN float bf2f(unsigned short b) {
  union { unsigned u; float f; } v; v.u = ((unsigned)b) << 16;
  return v.f;
}
// XOR swizzle inside a [rows][512B] LDS tile: 16B slot ^= (row&7)
DEVFN int swz(int row, int colbyte) {
  return row * 512 + ((((colbyte >> 4) ^ (row & 7)) << 4) | (colbyte & 15));
}
DEVFN float sigm(float x) { return __builtin_amdgcn_rcpf(1.f + __expf(-x)); }
DEVFN float tanhfast(float x) {
  float ax = fabsf(x);
  float e  = __expf(-2.f * ax);
  float t  = (1.f - e) * __builtin_amdgcn_rcpf(1.f + e);
  return copysignf(t, x);
}

DEVFN unsigned aload(const unsigned* p) {
  return __hip_atomic_load(p, __ATOMIC_RELAXED, __HIP_MEMORY_SCOPE_AGENT);
}

// Flat spin: reload ALL 16 dwords each round (idempotent; sentinel never
// re-stored). hv must hold an initial batch on entry.
DEVFN void spin16(unsigned hv[16], const unsigned* hs_tid) {
  while (true) {
    unsigned pend = 0;
#pragma unroll
    for (int k = 0; k < 16; ++k) pend |= (hv[k] == SENT) ? 1u : 0u;
    if (!pend) break;
#pragma unroll
    for (int k = 0; k < 16; ++k) hv[k] = aload(hs_tid + k * 128);
  }
}

// --------------------------------------------------------------------------
// Pack W[col][k] (K=256) into B-fragment tiles:
//   dst[((nt*8+kt)*64+lane)*8 + j] = bf16( W[nt*16+(lane&15)][kt*32+(lane>>4)*8+j] )
// grid = (ncols/16)*8 blocks of 64 threads.
// --------------------------------------------------------------------------
__global__ void pack_w(const float* __restrict__ w, unsigned short* __restrict__ dst) {
  int bid = blockIdx.x;           // nt*8 + kt
  int lane = threadIdx.x;
  int col = (bid >> 3) * 16 + (lane & 15);
  int k0  = (bid & 7) * 32 + (lane >> 4) * 8;
  const float* src = w + (size_t)col * 256 + k0;
  unsigned short* d = dst + ((size_t)bid * 64 + lane) * 8;
#pragma unroll
  for (int j = 0; j < 8; ++j) d[j] = f2bf(src[j]);
}

// --------------------------------------------------------------------------
// Dual-layer persistent LSTM. grid = 256 WGs x 128 thr (2 waves).
//   bid <  128 : layer 0, b = bid      (m = b&15, n = b>>4)
//   bid >= 128 : layer 1, b = bid-128
// bid%8 == m%8 for both halves -> all 16 WGs of an m-group share an XCD.
// Wave w owns unit-tile u16 = n*2+w (16 units x all 4 gates); W_ih and W_hh
// fragments register-resident (256 VGPRs). Per step:
//   L0: stage x[t] (prefetched) -> ih-MFMA while spinning h1[t-1] -> hh-MFMA
//       -> gates -> publish h1[t].
//   L1: spin h1[t] (ready in steady state) -> ih-MFMA while spinning h2[t-1]
//       -> hh-MFMA -> gates -> publish h2[t].
// h layout: [S][256 b][256 u] bf16, sentinel-initialized to 0xFFFFFFFF.
// --------------------------------------------------------------------------
__global__ __launch_bounds__(128, 1) void lstm_dual(
    const float* __restrict__ x,
    const unsigned short* __restrict__ Wih0, const unsigned short* __restrict__ Whh0,
    const float* __restrict__ bih0, const float* __restrict__ bhh0,
    const unsigned short* __restrict__ Wih1, const unsigned short* __restrict__ Whh1,
    const float* __restrict__ bih1, const float* __restrict__ bhh1,
    unsigned short* __restrict__ h1, unsigned short* __restrict__ h2)
{
  __shared__ char ldsA[8192];   // hh A-tile (h[t-1] of own layer)
  __shared__ char ldsB[8192];   // ih A-tile (x[t] or h1[t])
  const int tid = threadIdx.x;
  const int w = tid >> 6, lane = tid & 63;
  const bool isL1 = blockIdx.x >= 128;
  const int b = isL1 ? (int)blockIdx.x - 128 : (int)blockIdx.x;
  const int m = b & 15, n = b >> 4;
  const int u16 = n * 2 + w;            // unit-tile 0..15
  const int u   = u16 * 16 + (lane & 15);
  const int r0  = (lane >> 4) * 4;      // first of this lane's 4 C rows

  const unsigned short* Wih = isL1 ? Wih1 : Wih0;
  const unsigned short* Whh = isL1 ? Whh1 : Whh0;
  const float* bihp = isL1 ? bih1 : bih0;
  const float* bhhp = isL1 ? bhh1 : bhh0;
  unsigned short* hout = isL1 ? h2 : h1;

  // register-resident weight fragments: nt = g*16 + u16
  bf16x8 bwih[4][8], bwhh[4][8];
#pragma unroll
  for (int g = 0; g < 4; ++g)
#pragma unroll
    for (int kt = 0; kt < 8; ++kt) {
      bwih[g][kt] = *(const bf16x8*)(Wih +
          ((((size_t)(g * 16 + u16)) * 8 + kt) * 64 + lane) * 8);
      bwhh[g][kt] = *(const bf16x8*)(Whh +
          ((((size_t)(g * 16 + u16)) * 8 + kt) * 64 + lane) * 8);
    }

  float bias[4];
#pragma unroll
  for (int g = 0; g < 4; ++g) bias[g] = bihp[g * 256 + u] + bhhp[g * 256 + u];

  float c[4] = {0.f, 0.f, 0.f, 0.f};

  if (!isL1) {
    // ---------------- layer 0 ----------------
    const int xr = tid >> 3;            // tile row 0..15 (batch 16m+xr)
    const int xc = (tid & 7) * 32;      // 32 floats per thread
    float4 vv[8];
    {
      const float4* s = (const float4*)(x + ((size_t)(16 * m + xr) * 1024 + 0) * 256 + xc);
#pragma unroll
      for (int j = 0; j < 8; ++j) vv[j] = s[j];
    }

    for (int t = 0; t < 1024; ++t) {
      // stage x[t] (in vv) -> ldsB as bf16
#pragma unroll
      for (int s4 = 0; s4 < 4; ++s4) {
        uint4 o;
        o.x = f2bf(vv[2*s4].x)   | ((unsigned)f2bf(vv[2*s4].y)   << 16);
        o.y = f2bf(vv[2*s4].z)   | ((unsigned)f2bf(vv[2*s4].w)   << 16);
        o.z = f2bf(vv[2*s4+1].x) | ((unsigned)f2bf(vv[2*s4+1].y) << 16);
        o.w = f2bf(vv[2*s4+1].z) | ((unsigned)f2bf(vv[2*s4+1].w) << 16);
        *(uint4*)(&ldsB[swz(xr, xc * 2 + s4 * 16)]) = o;
      }
      // prefetch x[t+1]
      if (t < 1023) {
        const float4* s = (const float4*)(x + ((size_t)(16 * m + xr) * 1024 + (t + 1)) * 256 + xc);
#pragma unroll
        for (int j = 0; j < 8; ++j) vv[j] = s[j];
      }
      // issue h1[t-1] poll batch
      unsigned hv[16];
      const unsigned* hs_tid = nullptr;
      if (t > 0) {
        hs_tid = (const unsigned*)h1 + ((size_t)(t - 1) * 256 + 16 * m) * 128 + tid;
#pragma unroll
        for (int k = 0; k < 16; ++k) hv[k] = aload(hs_tid + k * 128);
      }
      __syncthreads();                   // ldsB ready / prev-step LDS reads done

      f32x4 acc[4];
#pragma unroll
      for (int g = 0; g < 4; ++g) acc[g] = (f32x4){0.f, 0.f, 0.f, 0.f};
#pragma unroll
      for (int kt = 0; kt < 8; ++kt) {   // ih-MFMA (overlaps spin latency)
        bf16x8 a = *(const bf16x8*)(&ldsB[swz(lane & 15, kt * 64 + (lane >> 4) * 16)]);
#pragma unroll
        for (int g = 0; g < 4; ++g)
          acc[g] = __builtin_amdgcn_mfma_f32_16x16x32_bf16(a, bwih[g][kt], acc[g], 0, 0, 0);
      }

      if (t > 0) {
        spin16(hv, hs_tid);
#pragma unroll
        for (int k = 0; k < 16; ++k)
          *(unsigned*)(&ldsA[swz(k, tid * 4)]) = hv[k];
        __syncthreads();
#pragma unroll
        for (int kt = 0; kt < 8; ++kt) { // hh-MFMA
          bf16x8 a = *(const bf16x8*)(&ldsA[swz(lane & 15, kt * 64 + (lane >> 4) * 16)]);
#pragma unroll
          for (int g = 0; g < 4; ++g)
            acc[g] = __builtin_amdgcn_mfma_f32_16x16x32_bf16(a, bwhh[g][kt], acc[g], 0, 0, 0);
        }
      } else {
        __syncthreads();                 // keep ldsB reuse guarded
      }

      // gates + publish h1[t]
      unsigned myh[4];
#pragma unroll
      for (int q = 0; q < 4; ++q) {
        float ia = acc[0][q] + bias[0];
        float fa = acc[1][q] + bias[1];
        float ga = acc[2][q] + bias[2];
        float oa = acc[3][q] + bias[3];
        c[q] = sigm(fa) * c[q] + sigm(ia) * tanhfast(ga);
        myh[q] = (unsigned)f2bf(sigm(oa) * tanhfast(c[q]));
      }
#pragma unroll
      for (int q = 0; q < 4; ++q) {
        unsigned ov = (unsigned)__shfl_xor((int)myh[q], 1, 64);
        if ((lane & 1) == 0) {
          unsigned word = (myh[q] & 0xFFFFu) | (ov << 16);
          unsigned* hp = (unsigned*)h1 + (((size_t)t * 256 + 16 * m + r0 + q) * 256 + u) / 2;
          __hip_atomic_store(hp, word, __ATOMIC_RELAXED, __HIP_MEMORY_SCOPE_AGENT);
        }
      }
    }
  } else {
    // ---------------- layer 1 ----------------
    for (int t = 0; t < 1024; ++t) {
      unsigned hv1[16], hv2[16];
      const unsigned* hs1_tid = (const unsigned*)h1 + ((size_t)t * 256 + 16 * m) * 128 + tid;
      const unsigned* hs2_tid = nullptr;
#pragma unroll
      for (int k = 0; k < 16; ++k) hv1[k] = aload(hs1_tid + k * 128);
      if (t > 0) {
        hs2_tid = (const unsigned*)h2 + ((size_t)(t - 1) * 256 + 16 * m) * 128 + tid;
#pragma unroll
        for (int k = 0; k < 16; ++k) hv2[k] = aload(hs2_tid + k * 128);
      }

      spin16(hv1, hs1_tid);              // h1[t] — ready in steady state
#pragma unroll
      for (int k = 0; k < 16; ++k)
        *(unsigned*)(&ldsB[swz(k, tid * 4)]) = hv1[k];
      __syncthreads();

      f32x4 acc[4];
#pragma unroll
      for (int g = 0; g < 4; ++g) acc[g] = (f32x4){0.f, 0.f, 0.f, 0.f};
#pragma unroll
      for (int kt = 0; kt < 8; ++kt) {   // ih-MFMA (overlaps h2 spin latency)
        bf16x8 a = *(const bf16x8*)(&ldsB[swz(lane & 15, kt * 64 + (lane >> 4) * 16)]);
#pragma unroll
        for (int g = 0; g < 4; ++g)
          acc[g] = __builtin_amdgcn_mfma_f32_16x16x32_bf16(a, bwih[g][kt], acc[g], 0, 0, 0);
      }

      if (t > 0) {
        spin16(hv2, hs2_tid);
#pragma unroll
        for (int k = 0; k < 16; ++k)
          *(unsigned*)(&ldsA[swz(k, tid * 4)]) = hv2[k];
        __syncthreads();
#pragma unroll
        for (int kt = 0; kt < 8; ++kt) { // hh-MFMA
          bf16x8 a = *(const bf16x8*)(&ldsA[swz(lane & 15, kt * 64 + (lane >> 4) * 16)]);
#pragma unroll
          for (int g = 0; g < 4; ++g)
            acc[g] = __builtin_amdgcn_mfma_f32_16x16x32_bf16(a, bwhh[g][kt], acc[g], 0, 0, 0);
        }
      } else {
        __syncthreads();
      }

      // gates + publish h2[t]
      unsigned myh[4];
#pragma unroll
      for (int q = 0; q < 4; ++q) {
        float ia = acc[0][q] + bias[0];
        float fa = acc[1][q] + bias[1];
        float ga = acc[2][q] + bias[2];
        float oa = acc[3][q] + bias[3];
        c[q] = sigm(fa) * c[q] + sigm(ia) * tanhfast(ga);
        myh[q] = (unsigned)f2bf(sigm(oa) * tanhfast(c[q]));
      }
#pragma unroll
      for (int q = 0; q < 4; ++q) {
        unsigned ov = (unsigned)__shfl_xor((int)myh[q], 1, 64);
        if ((lane & 1) == 0) {
          unsigned word = (myh[q] & 0xFFFFu) | (ov << 16);
          unsigned* hp = (unsigned*)h2 + (((size_t)t * 256 + 16 * m + r0 + q) * 256 + u) / 2;
          __hip_atomic_store(hp, word, __ATOMIC_RELAXED, __HIP_MEMORY_SCOPE_AGENT);
        }
      }
    }
  }
}

// --------------------------------------------------------------------------
// logits = h2 @ fc_w^T + fc_b; out = logits - logsumexp(logits) (rows of 256).
// Block = 256 thr (4 waves); tile = 64 rows (fixed t, 64 b's) x 256 cols.
// grid = 4096 (t = bid>>2, b0 = (bid&3)*64).
// --------------------------------------------------------------------------
__global__ __launch_bounds__(256, 1) void fc_lsm(
    const unsigned short* __restrict__ h2,
    const unsigned short* __restrict__ Bp,
    const float* __restrict__ fcb,
    float* __restrict__ out)
{
  const int tid = threadIdx.x;
  const int wid = tid >> 6, lane = tid & 63;
  const int t = blockIdx.x >> 2, b0 = (blockIdx.x & 3) * 64;

  f32x4 acc[16];
#pragma unroll
  for (int nt = 0; nt < 16; ++nt) acc[nt] = (f32x4){0.f, 0.f, 0.f, 0.f};

#pragma unroll
  for (int kt = 0; kt < 8; ++kt) {
    bf16x8 a = *(const bf16x8*)(h2 +
        (((size_t)t * 256 + b0 + wid * 16 + (lane & 15)) * 256 +
         kt * 32 + (lane >> 4) * 8));
#pragma unroll
    for (int nt = 0; nt < 16; ++nt) {
      bf16x8 b = *(const bf16x8*)(Bp + (((size_t)nt * 8 + kt) * 64 + lane) * 8);
      acc[nt] = __builtin_amdgcn_mfma_f32_16x16x32_bf16(a, b, acc[nt], 0, 0, 0);
    }
  }
#pragma unroll
  for (int nt = 0; nt < 16; ++nt) {
    float bias = fcb[nt * 16 + (lane & 15)];
#pragma unroll
    for (int q = 0; q < 4; ++q) acc[nt][q] += bias;
  }

  float mx[4] = {-1e30f, -1e30f, -1e30f, -1e30f};
#pragma unroll
  for (int nt = 0; nt < 16; ++nt)
#pragma unroll
    for (int q = 0; q < 4; ++q) mx[q] = fmaxf(mx[q], acc[nt][q]);
#pragma unroll
  for (int d = 1; d < 16; d <<= 1)
#pragma unroll
    for (int q = 0; q < 4; ++q) mx[q] = fmaxf(mx[q], __shfl_xor(mx[q], d, 64));

  float sm[4] = {0.f, 0.f, 0.f, 0.f};
#pragma unroll
  for (int nt = 0; nt < 16; ++nt)
#pragma unroll
    for (int q = 0; q < 4; ++q) sm[q] += __expf(acc[nt][q] - mx[q]);
#pragma unroll
  for (int d = 1; d < 16; d <<= 1)
#pragma unroll
    for (int q = 0; q < 4; ++q) sm[q] += __shfl_xor(sm[q], d, 64);

  float lse[4];
#pragma unroll
  for (int q = 0; q < 4; ++q) lse[q] = mx[q] + __logf(sm[q]);

#pragma unroll
  for (int nt = 0; nt < 16; ++nt) {
#pragma unroll
    for (int q = 0; q < 4; ++q) {
      int b = b0 + wid * 16 + (lane >> 4) * 4 + q;
      out[((size_t)b * 1024 + t) * 256 + nt * 16 + (lane & 15)] = acc[nt][q] - lse[q];
    }
  }
}

// Unambiguous marker if workspace is too small.
__global__ void fill_marker(float* out, size_t nvals) {
  size_t i = (size_t)blockIdx.x * blockDim.x + threadIdx.x;
  if (i < nvals) out[i] = -7777.0f;
}

// --------------------------------------------------------------------------
extern "C" void kernel_launch(void* const* d_in, const int* in_sizes, int n_in,
                              void* d_out, int out_size, void* d_ws, size_t ws_size,
                              hipStream_t stream)
{
  (void)in_sizes; (void)n_in;
  const float* x    = (const float*)d_in[0];
  const float* wih0 = (const float*)d_in[1];
  const float* whh0 = (const float*)d_in[2];
  const float* bih0 = (const float*)d_in[3];
  const float* bhh0 = (const float*)d_in[4];
  const float* wih1 = (const float*)d_in[5];
  const float* whh1 = (const float*)d_in[6];
  const float* bih1 = (const float*)d_in[7];
  const float* bhh1 = (const float*)d_in[8];
  const float* fcw  = (const float*)d_in[9];
  const float* fcb  = (const float*)d_in[10];
  float* out = (float*)d_out;

  // workspace layout (bytes)
  const size_t o_wp0i = 0;
  const size_t o_wp0h = o_wp0i + 524288;
  const size_t o_wp1i = o_wp0h + 524288;
  const size_t o_wp1h = o_wp1i + 524288;
  const size_t o_fcp  = o_wp1h + 524288;        // 131072
  const size_t o_h1   = o_fcp  + 131072;        // 134217728
  const size_t o_h2   = o_h1   + 134217728;     // 134217728
  const size_t need   = o_h2   + 134217728;     // ~271 MB

  if (ws_size < need) {
    size_t nv = (size_t)out_size;
    fill_marker<<<(unsigned)((nv + 1023) / 1024), 1024, 0, stream>>>(out, nv);
    return;
  }

  char* ws = (char*)d_ws;
  unsigned short* wp0i = (unsigned short*)(ws + o_wp0i);
  unsigned short* wp0h = (unsigned short*)(ws + o_wp0h);
  unsigned short* wp1i = (unsigned short*)(ws + o_wp1i);
  unsigned short* wp1h = (unsigned short*)(ws + o_wp1h);
  unsigned short* fcp  = (unsigned short*)(ws + o_fcp);
  unsigned short* h1   = (unsigned short*)(ws + o_h1);
  unsigned short* h2   = (unsigned short*)(ws + o_h2);

  pack_w<<<512, 64, 0, stream>>>(wih0, wp0i);
  pack_w<<<512, 64, 0, stream>>>(whh0, wp0h);
  pack_w<<<512, 64, 0, stream>>>(wih1, wp1i);
  pack_w<<<512, 64, 0, stream>>>(whh1, wp1h);
  pack_w<<<128, 64, 0, stream>>>(fcw,  fcp);

  // sentinel-init both h buffers (0xFF bytes -> 0xFFFFFFFF dwords)
  hipMemsetAsync(h1, 0xFF, 134217728, stream);
  hipMemsetAsync(h2, 0xFF, 134217728, stream);

  lstm_dual<<<256, 128, 0, stream>>>(x, wp0i, wp0h, bih0, bhh0,
                                     wp1i, wp1h, bih1, bhh1, h1, h2);

  fc_lsm<<<4096, 256, 0, stream>>>(h2, fcp, fcb, out);
}